// Round 16
// baseline (918.959 us; speedup 1.0000x reference)
//
#include <hip/hip_runtime.h>
#include <cstddef>
#include <cstdint>

#define DEVINL __device__ __forceinline__

typedef __attribute__((ext_vector_type(8))) _Float16 half8v;
typedef __attribute__((ext_vector_type(4))) _Float16 half4v;
typedef __attribute__((ext_vector_type(16))) float f32x16;

constexpr int cmax(int a, int b) { return a > b ? a : b; }

// ---------------------------------------------------------------------------
// SPN forward, MI355X gfx950. B=4, H=W=256, NF=32.
// Round 16: round-15 design with the k_packall grid fix (1152 blocks covers
// the largest pack: c4w = 294912 entries).
// ---------------------------------------------------------------------------

// ---------- merged weight pack: blockIdx.y = pack id ----------
__global__ __launch_bounds__(256) void k_packall(
    const float* __restrict__ mw, const float* __restrict__ c1w,
    const float* __restrict__ pw,
    const float* __restrict__ c2w, const float* __restrict__ c3w,
    const float* __restrict__ c4w, const float* __restrict__ d2w,
    const float* __restrict__ d4w, const float* __restrict__ d6w,
    const float* __restrict__ d7w, char* __restrict__ wz)
{
  const int p = blockIdx.y;
  const int e = blockIdx.x * 256 + threadIdx.x;
  if (p < 3) {
    const float* src = (p == 0) ? mw : (p == 1) ? c1w : pw;
    const int ci = (p == 2) ? 32 : 3;
    const int co = (p == 2) ? 3 : 32;
    const int n = co * ci * 9;
    if (e >= n) return;
    float* dst = (float*)wz + (p == 0 ? 0 : (p == 1 ? 864 : 1728));
    int cco = e / (ci * 9);
    int r   = e - cco * ci * 9;
    int cci = r / 9;
    int k   = r - cci * 9;
    dst[(cci * 9 + k) * co + cco] = src[e];
  } else {
    const float* src; int ci, co; size_t off;
    switch (p) {
      case 3:  src = c2w; ci = 32;  co = 64;  off = 0;      break;
      case 4:  src = c3w; ci = 64;  co = 128; off = 19456;  break;
      case 5:  src = c4w; ci = 128; co = 256; off = 97280;  break;
      case 6:  src = d2w; ci = 128; co = 128; off = 408576; break;
      case 7:  src = d4w; ci = 128; co = 64;  off = 564224; break;
      case 8:  src = d6w; ci = 64;  co = 32;  off = 642048; break;
      default: src = d7w; ci = 32;  co = 384; off = 661504; break;
    }
    int chunks = ci >> 4;
    int total = co * chunks * 144;
    if (e >= total) return;
    _Float16* dst = (_Float16*)(wz + 2592 * 4) + off;
    int n  = e / (chunks * 144);
    int r2 = e - n * chunks * 144;
    int cb = r2 / 144;
    int k  = r2 - cb * 144;
    int tap = k >> 4, cci = k & 15;
    float v = src[((size_t)n * ci + cb * 16 + cci) * 9 + tap];
    dst[((size_t)cb * co + n) * 152 + k] = (_Float16)v;
  }
}

// ---------- fp16 MFMA implicit-GEMM conv 3x3 pad 1, stage-once halo ----------
// Tile: MT = NWM*32 pixels = (MT/TW) rows x TW cols. TW=16 default; TW=4 for
// MODE 2 (transposed-gate stores become 64B contiguous along y).
// GATES=1: blockIdx.y selects direction half: nb = n0 + y*96, out = y? outv2 : outv.
template<int NWM, int NACC, int CHUNKS, int MODE, int GATES, int TW = 16>
__global__ __launch_bounds__(NWM * 64) void k_convh(
    const float* __restrict__ in, const _Float16* __restrict__ wpk,
    const float* __restrict__ bias, const float* __restrict__ skip,
    void* __restrict__ outv, void* __restrict__ outv2,
    int H, int W, int wCout, int n0, int outC, int oco0)
{
  static_assert(GATES == 0 || NACC == 3, "GATES needs NACC==3");
  static_assert(TW == 16 || MODE == 2, "narrow tile only for MODE 2");
  constexpr int NTHR = NWM * 64;
  constexpr int MT = NWM * 32;
  constexpr int RT = MT / TW;
  constexpr int RHh = RT + 2;
  constexpr int CW = TW + 2;
  constexpr int AENT = RHh * CW;
  constexpr int N_BLK = NACC * 32;
  constexpr int APS = 24;
  constexpr int A_BYTES = AENT * APS * 2;
  constexpr int B_BYTES = N_BLK * 152 * 2;
  constexpr int MPF = MT + 2;
  constexpr int MPH = 132;
  constexpr int EP_BYTES = GATES ? (96 * MPH * 2) : (N_BLK * MPF * 4);
  constexpr int SMEM = cmax(A_BYTES + B_BYTES, EP_BYTES);

  const int tid = threadIdx.x;
  const int wave = tid >> 6, lane = tid & 63;
  const int wm = wave;
  const int tiles_x = W / TW;
  const int tx0 = (blockIdx.x % tiles_x) * TW;
  const int ty0 = (blockIdx.x / tiles_x) * RT;
  const int b = blockIdx.z;
  const int nb = n0 + blockIdx.y * N_BLK;
  const int ocb = oco0 + blockIdx.y * N_BLK;

  __shared__ __align__(16) char smem[SMEM];
  _Float16* Ah = (_Float16*)smem;
  _Float16* Bh = (_Float16*)(smem + A_BYTES);

  f32x16 acc[NACC] = {};

  const size_t ps = (size_t)H * W;
  const float* inb = in + (size_t)b * (CHUNKS * 16) * ps;

  for (int cb = 0; cb < CHUNKS; ++cb) {
    __syncthreads();
    // ---- stage A: halo tile, 16 channels ----
    for (int e = tid; e < AENT; e += NTHR) {
      int r = e / CW, c = e - r * CW;
      int gy = ty0 + r - 1, gx = tx0 + c - 1;
      bool ok = (unsigned)gy < (unsigned)H && (unsigned)gx < (unsigned)W;
      const float* src = inb + (size_t)(cb * 16) * ps + (size_t)gy * W + gx;
      half8v v0, v1;
#pragma unroll
      for (int j = 0; j < 8; ++j)
        v0[j] = ok ? (_Float16)src[(size_t)j * ps] : (_Float16)0.f;
#pragma unroll
      for (int j = 0; j < 8; ++j)
        v1[j] = ok ? (_Float16)src[(size_t)(j + 8) * ps] : (_Float16)0.f;
      *(half8v*)&Ah[e * APS] = v0;
      *(half8v*)&Ah[e * APS + 8] = v1;
    }
    // ---- stage B (per chunk) ----
    {
      const _Float16* wsrc = wpk + ((size_t)cb * wCout + nb) * 152;
      for (int e = tid; e < N_BLK * 19; e += NTHR)
        *(uint4*)&Bh[e * 8] = *(const uint4*)(wsrc + e * 8);
    }
    __syncthreads();
    // ---- MFMA: 9 shifted tap-reads x NACC ----
    const int am = wm * 32 + (lane & 31);
    const int r0 = am / TW, c0 = am % TW;
    const int kh = lane >> 5;
    const _Float16* Ab = Ah + kh * 8;
    const _Float16* Bb = Bh + kh * 8;
#pragma unroll
    for (int ks = 0; ks < 9; ++ks) {
      const int dy = ks / 3, dx = ks - dy * 3;
      half8v af = *(const half8v*)(Ab + ((r0 + dy) * CW + (c0 + dx)) * APS);
#pragma unroll
      for (int na = 0; na < NACC; ++na) {
        const int bn = na * 32 + (lane & 31);
        half8v bf = *(const half8v*)(Bb + bn * 152 + ks * 16);
        acc[na] = __builtin_amdgcn_mfma_f32_32x32x16_f16(af, bf, acc[na], 0, 0, 0);
      }
    }
  }

  __syncthreads();

  if (GATES) {
    _Float16* EPH = (_Float16*)smem;
    const int c = lane & 31;
    const float bv0 = bias[nb + c];
    const float bv1 = bias[nb + 32 + c];
    const float bv2 = bias[nb + 64 + c];
#pragma unroll
    for (int i = 0; i < 16; ++i) {
      int m = wm * 32 + (i & 3) + 8 * (i >> 2) + 4 * (lane >> 5);
      float g1 = acc[0][i] + bv0;
      float g2 = acc[GATES ? 1 : 0][i] + bv1;
      float g3 = acc[GATES ? 2 : 0][i] + bv2;
      float s = fabsf(g1) + fabsf(g2) + fabsf(g3);
      if (s >= 1.f) { float r = 1.f / s; g1 *= r; g2 *= r; g3 *= r; }
      EPH[(size_t)(0 * 32 + c) * MPH + m] = (_Float16)g1;
      EPH[(size_t)(1 * 32 + c) * MPH + m] = (_Float16)g2;
      EPH[(size_t)(2 * 32 + c) * MPH + m] = (_Float16)g3;
    }
    __syncthreads();
    _Float16* outh = (_Float16*)(blockIdx.y ? outv2 : outv);
    if (MODE == 2) {
      // transposed plane [gc][x][y]: per (gc,x) RT contiguous y values
      const int TOT = 96 * TW;
      for (int r = tid; r < TOT; r += NTHR) {
        int gc = r / TW, x = r % TW;
        const _Float16* ep = EPH + (size_t)gc * MPH + x;
        _Float16 v[RT];
#pragma unroll
        for (int y = 0; y < RT; ++y) v[y] = ep[y * TW];
        size_t base = ((size_t)(b * 96 + gc) * W + tx0 + x) * (size_t)H + ty0;
#pragma unroll
        for (int j = 0; j < RT / 8; ++j)
          *(uint4*)(outh + base + j * 8) = *(const uint4*)(v + j * 8);
      }
    } else {
      const int TOT = 96 * RT;
      for (int r = tid; r < TOT; r += NTHR) {
        int gc = r / RT, y = r - gc * RT;
        const uint2* ep = (const uint2*)(EPH + (size_t)gc * MPH + y * TW);
        uint2 v0 = ep[0], v1 = ep[1], v2 = ep[2], v3 = ep[3];
        size_t base = ((size_t)(b * 96 + gc) * H + ty0 + y) * (size_t)W + tx0;
        *(uint2*)(outh + base + 0)  = v0;
        *(uint2*)(outh + base + 4)  = v1;
        *(uint2*)(outh + base + 8)  = v2;
        *(uint2*)(outh + base + 12) = v3;
      }
    }
  } else {
    float* EP = (float*)smem;
    float bv[NACC];
#pragma unroll
    for (int na = 0; na < NACC; ++na) bv[na] = bias[nb + na * 32 + (lane & 31)];
#pragma unroll
    for (int na = 0; na < NACC; ++na) {
      const int c = na * 32 + (lane & 31);
#pragma unroll
      for (int i = 0; i < 16; ++i) {
        int m = wm * 32 + (i & 3) + 8 * (i >> 2) + 4 * (lane >> 5);
        EP[(size_t)c * MPF + m] = acc[na][i] + bv[na];
      }
    }
    __syncthreads();
    float* out = (float*)outv;
    const int TOT = N_BLK * RT;
    for (int r = tid; r < TOT; r += NTHR) {
      int c = r / RT, y = r - c * RT;
      const float2* ep = (const float2*)(EP + (size_t)c * MPF + y * 16);
      float v[16];
#pragma unroll
      for (int j = 0; j < 8; ++j) {
        float2 t = ep[j];
        v[2 * j] = t.x; v[2 * j + 1] = t.y;
      }
      size_t base = (((size_t)b * outC + ocb + c) * H + ty0 + y) * (size_t)W + tx0;
      if (MODE == 1) {
#pragma unroll
        for (int j = 0; j < 4; ++j) {
          float4 sk = *(const float4*)(skip + base + 4 * j);
          float e0 = v[4*j+0] > 0.f ? v[4*j+0] : expm1f(v[4*j+0]);
          float e1 = v[4*j+1] > 0.f ? v[4*j+1] : expm1f(v[4*j+1]);
          float e2 = v[4*j+2] > 0.f ? v[4*j+2] : expm1f(v[4*j+2]);
          float e3 = v[4*j+3] > 0.f ? v[4*j+3] : expm1f(v[4*j+3]);
          v[4*j+0] = e0 + sk.x; v[4*j+1] = e1 + sk.y;
          v[4*j+2] = e2 + sk.z; v[4*j+3] = e3 + sk.w;
        }
      }
#pragma unroll
      for (int j = 0; j < 4; ++j)
        *(float4*)(out + base + 4 * j) = *(const float4*)(v + 4 * j);
    }
  }
}

// ---------- f32 tiled conv 3x3 (small convs + final) ----------
template<int CI, int CO>
__global__ __launch_bounds__(256) void k_conv3x3f(
    const float* __restrict__ in, const float* __restrict__ wr,
    const float* __restrict__ bias, float* __restrict__ out,
    int Cin, int H, int W, int wstride, int outC)
{
  const int ntx = W >> 4;
  const int tid = threadIdx.x;
  const int tx = tid & 15, ty = tid >> 4;
  const int tx0 = (blockIdx.x % ntx) << 4, ty0 = (blockIdx.x / ntx) << 4;
  const int b = blockIdx.z;

  __shared__ float sh[CI * 324];

  float acc[CO];
#pragma unroll
  for (int co = 0; co < CO; ++co) acc[co] = bias[co];

  const float* inb = in + (size_t)b * Cin * H * W;

  for (int cb = 0; cb < Cin; cb += CI) {
    __syncthreads();
    for (int e = tid; e < CI * 324; e += 256) {
      int ci = e / 324;
      int rr = e - ci * 324;
      int r = rr / 18, c = rr - r * 18;
      int gh = ty0 + r - 1, gw = tx0 + c - 1;
      float v = 0.f;
      if ((unsigned)gh < (unsigned)H && (unsigned)gw < (unsigned)W)
        v = inb[(size_t)(cb + ci) * H * W + (size_t)gh * W + gw];
      sh[e] = v;
    }
    __syncthreads();
#pragma unroll 1
    for (int ci = 0; ci < CI; ++ci) {
      float v[9];
      const float* sp = sh + ci * 324 + ty * 18 + tx;
#pragma unroll
      for (int kh = 0; kh < 3; ++kh)
#pragma unroll
        for (int kw = 0; kw < 3; ++kw)
          v[kh * 3 + kw] = sp[kh * 18 + kw];
      const float* wp = wr + (size_t)((cb + ci) * 9) * wstride;
#pragma unroll
      for (int k = 0; k < 9; ++k)
#pragma unroll
        for (int co = 0; co < CO; ++co)
          acc[co] = fmaf(wp[(size_t)k * wstride + co], v[k], acc[co]);
    }
  }
#pragma unroll
  for (int co = 0; co < CO; ++co)
    out[(((size_t)b * outC + co) * H + ty0 + ty) * W + tx0 + tx] = acc[co];
}

// ---------- max of 4 scan outputs -> f32 natural buffer ----------
__global__ __launch_bounds__(256) void k_max4(
    const _Float16* __restrict__ om1, const _Float16* __restrict__ om2,
    const _Float16* __restrict__ omT1, const _Float16* __restrict__ omT2,
    float* __restrict__ out)
{
  __shared__ float t[32][33];
  const int z = blockIdx.z;
  const int x0 = blockIdx.x * 32, y0 = blockIdx.y * 32;
  const int tx = threadIdx.x & 31, ty = threadIdx.x >> 5;
  const size_t ps = 65536;
  const size_t zb = (size_t)z * ps;
#pragma unroll
  for (int j = 0; j < 32; j += 8) {
    size_t p = zb + (size_t)(x0 + ty + j) * 256 + (y0 + tx);
    t[ty + j][tx] = fmaxf((float)omT1[p], (float)omT2[p]);
  }
  __syncthreads();
#pragma unroll
  for (int j = 0; j < 32; j += 8) {
    size_t p = zb + (size_t)(y0 + ty + j) * 256 + (x0 + tx);
    float v = fmaxf((float)om1[p], (float)om2[p]);
    out[p] = fmaxf(v, t[tx][ty + j]);
  }
}

// ---------- conv 1x1 (f32) ----------
__global__ __launch_bounds__(256) void k_conv1x1(
    const float* __restrict__ in, const float* __restrict__ wgt,
    const float* __restrict__ bias, float* __restrict__ out,
    int Cin, int Cout, int H, int W)
{
  int hw = blockIdx.x * 256 + threadIdx.x;
  if (hw >= H * W) return;
  int co = blockIdx.y, b = blockIdx.z;
  const float* ip = in + (size_t)b * Cin * H * W + hw;
  const float* wp = wgt + (size_t)co * Cin;
  float acc = bias[co];
  for (int ci = 0; ci < Cin; ++ci) acc += wp[ci] * ip[(size_t)ci * H * W];
  out[((size_t)b * Cout + co) * H * W + hw] = acc;
}

// ---------- relu + maxpool 3x3 stride 2 pad 1 ----------
__global__ __launch_bounds__(256) void k_pool(
    const float* __restrict__ in, float* __restrict__ out, int C, int H, int W)
{
  int Ho = H >> 1, Wo = W >> 1;
  int hw = blockIdx.x * 256 + threadIdx.x;
  if (hw >= Ho * Wo) return;
  int ow = hw % Wo, oh = hw / Wo;
  int c = blockIdx.y, b = blockIdx.z;
  const float* p = in + ((size_t)(b * C + c) * H) * W;
  float m = 0.f;
#pragma unroll
  for (int dh = -1; dh <= 1; ++dh) {
    int ih = 2 * oh + dh;
    if ((unsigned)ih >= (unsigned)H) continue;
    const float* r = p + (size_t)ih * W;
#pragma unroll
    for (int dw = -1; dw <= 1; ++dw) {
      int iw = 2 * ow + dw;
      if ((unsigned)iw >= (unsigned)W) continue;
      m = fmaxf(m, r[iw]);
    }
  }
  out[((size_t)(b * C + c) * Ho + oh) * Wo + ow] = m;
}

// ---------- bilinear 2x upsample ----------
__global__ __launch_bounds__(256) void k_up2(
    const float* __restrict__ in, float* __restrict__ out, int C, int H, int W)
{
  int Ho = H * 2, Wo = W * 2;
  int hw = blockIdx.x * 256 + threadIdx.x;
  if (hw >= Ho * Wo) return;
  int ow = hw % Wo, oh = hw / Wo;
  int c = blockIdx.y, b = blockIdx.z;
  int ih = oh >> 1, iw = ow >> 1;
  int ih0, ih1, iw0, iw1; float fh0, fw0;
  if (oh & 1) { ih0 = ih; ih1 = min(ih + 1, H - 1); fh0 = 0.75f; }
  else        { ih0 = max(ih - 1, 0); ih1 = ih;     fh0 = 0.25f; }
  if (ow & 1) { iw0 = iw; iw1 = min(iw + 1, W - 1); fw0 = 0.75f; }
  else        { iw0 = max(iw - 1, 0); iw1 = iw;     fw0 = 0.25f; }
  const float* p = in + ((size_t)(b * C + c) * H) * W;
  float v = fh0 * (fw0 * p[(size_t)ih0 * W + iw0] + (1.f - fw0) * p[(size_t)ih0 * W + iw1])
          + (1.f - fh0) * (fw0 * p[(size_t)ih1 * W + iw0] + (1.f - fw0) * p[(size_t)ih1 * W + iw1]);
  out[((size_t)(b * C + c) * Ho + oh) * Wo + ow] = v;
}

// ---------- X f32 -> fp16 natural + fp16 transposed ----------
__global__ void k_xcvt(const float* __restrict__ in, _Float16* __restrict__ xn,
                       _Float16* __restrict__ xt)
{
  __shared__ _Float16 t[32][33];
  int z = blockIdx.z;
  int x0 = blockIdx.x * 32, y0 = blockIdx.y * 32;
  int tx = threadIdx.x, ty = threadIdx.y;
  const float* ip = in + (size_t)z * 65536;
#pragma unroll
  for (int j = 0; j < 32; j += 8) {
    float v = ip[(size_t)(y0 + ty + j) * 256 + x0 + tx];
    xn[(size_t)z * 65536 + (size_t)(y0 + ty + j) * 256 + x0 + tx] = (_Float16)v;
    t[ty + j][tx] = (_Float16)v;
  }
  __syncthreads();
#pragma unroll
  for (int j = 0; j < 32; j += 8)
    xt[(size_t)z * 65536 + (size_t)(x0 + ty + j) * 256 + y0 + tx] = t[tx][ty + j];
}

// ---------- gated scan core: chunk-contiguous lanes, 2 shuffles/step ----------
DEVINL void gl_lds16p(const void* g, void* lds) {
  __builtin_amdgcn_global_load_lds(
      (const __attribute__((address_space(1))) unsigned int*)g,
      (__attribute__((address_space(3))) unsigned int*)lds, 16, 0, 0);
}

template<int REV>
DEVINL void prop_core(const _Float16* xp, const _Float16* g1,
                      const _Float16* g2, const _Float16* g3,
                      _Float16* op, int S, int P, int lane,
                      _Float16* bx, _Float16* h1, _Float16* h2, _Float16* h3)
{
  float r0 = 0.f, r1 = 0.f, r2 = 0.f, r3 = 0.f;
  int cur = 0;

  auto stage = [&](int buf, int s0) {
#pragma unroll
    for (int v = 0; v < 8; ++v) {
      size_t ro = (size_t)(s0 + 2 * v) * P + lane * 8;
      gl_lds16p(xp + ro, bx + buf * 4096 + v * 512);
      gl_lds16p(g1 + ro, h1 + buf * 4096 + v * 512);
      gl_lds16p(g2 + ro, h2 + buf * 4096 + v * 512);
      gl_lds16p(g3 + ro, h3 + buf * 4096 + v * 512);
    }
  };

  stage(0, REV ? (S - 16) : 0);
  const int NT = S / 16;
  for (int t = 0; t < NT; ++t) {
    const int s0 = REV ? (S - 16 - t * 16) : (t * 16);
    asm volatile("s_waitcnt vmcnt(0)" ::: "memory");
    if (t + 1 < NT) stage(cur ^ 1, REV ? (s0 - 16) : (s0 + 16));

#pragma unroll
    for (int u = 0; u < 16; ++u) {
      const int e = REV ? (15 - u) : u;
      half4v xv = *(const half4v*)(bx + cur * 4096 + e * 256 + 4 * lane);
      half4v a1 = *(const half4v*)(h1 + cur * 4096 + e * 256 + 4 * lane);
      half4v a2 = *(const half4v*)(h2 + cur * 4096 + e * 256 + 4 * lane);
      half4v a3 = *(const half4v*)(h3 + cur * 4096 + e * 256 + 4 * lane);

      float hu0 = __shfl_up(r3, 1);
      float hd3 = __shfl_down(r0, 1);
      if (lane == 0)  hu0 = 0.f;
      if (lane == 63) hd3 = 0.f;

      float o0 = r0, o1 = r1, o2 = r2, o3v = r3;
      float x0 = xv[0], x1 = xv[1], x2 = xv[2], x3 = xv[3];
      float a10 = a1[0], a11 = a1[1], a12 = a1[2], a13 = a1[3];
      float a20 = a2[0], a21 = a2[1], a22 = a2[2], a23 = a2[3];
      float a30 = a3[0], a31 = a3[1], a32 = a3[2], a33 = a3[3];

      r0 = (1.f - a10 - a20 - a30) * x0 + a10 * hu0 + a20 * o0 + a30 * o1;
      r1 = (1.f - a11 - a21 - a31) * x1 + a11 * o0  + a21 * o1 + a31 * o2;
      r2 = (1.f - a12 - a22 - a32) * x2 + a12 * o1  + a22 * o2 + a32 * o3v;
      r3 = (1.f - a13 - a23 - a33) * x3 + a13 * o2  + a23 * o3v + a33 * hd3;

      half4v hv; hv[0] = (_Float16)r0; hv[1] = (_Float16)r1;
      hv[2] = (_Float16)r2; hv[3] = (_Float16)r3;
      *(half4v*)(op + (size_t)(s0 + e) * P + 4 * lane) = hv;
    }
    cur ^= 1;
  }
}

// dir = blockIdx.x>>7: 0 -> fwd (GA -> omA), 1 -> rev (GB -> omB).
__global__ __launch_bounds__(64) void k_prop_pair(
    const _Float16* __restrict__ Xh,
    const _Float16* __restrict__ GA, const _Float16* __restrict__ GB,
    _Float16* __restrict__ omA, _Float16* __restrict__ omB, int S, int P)
{
  const int dir = blockIdx.x >> 7;
  const int plane = blockIdx.x & 127;
  const int b = plane >> 5, c = plane & 31;
  const int lane = threadIdx.x;
  const size_t ps = (size_t)S * P;

  __shared__ __align__(16) _Float16 bx[2 * 4096];
  __shared__ __align__(16) _Float16 h1[2 * 4096];
  __shared__ __align__(16) _Float16 h2[2 * 4096];
  __shared__ __align__(16) _Float16 h3[2 * 4096];

  const _Float16* xp = Xh + (size_t)plane * ps;
  const _Float16* G = dir ? GB : GA;
  const _Float16* g1 = G + ((size_t)b * 96 + c) * ps;
  const _Float16* g2 = g1 + (size_t)32 * ps;
  const _Float16* g3 = g1 + (size_t)64 * ps;
  _Float16* op = (dir ? omB : omA) + (size_t)plane * ps;

  if (dir == 0) prop_core<0>(xp, g1, g2, g3, op, S, P, lane, bx, h1, h2, h3);
  else          prop_core<1>(xp, g1, g2, g3, op, S, P, lane, bx, h1, h2, h3);
}

// ---------------------------------------------------------------------------
extern "C" void kernel_launch(void* const* d_in, const int* in_sizes, int n_in,
                              void* d_out, int out_size, void* d_ws, size_t ws_size,
                              hipStream_t stream)
{
  const float* x   = (const float*)d_in[0];
  const float* rgb = (const float*)d_in[1];
  const float* mw  = (const float*)d_in[2];
  const float* mb  = (const float*)d_in[3];
  const float* c1w = (const float*)d_in[4];
  const float* c1b = (const float*)d_in[5];
  const float* c2w = (const float*)d_in[6];
  const float* c2b = (const float*)d_in[7];
  const float* c3w = (const float*)d_in[8];
  const float* c3b = (const float*)d_in[9];
  const float* c4w = (const float*)d_in[10];
  const float* c4b = (const float*)d_in[11];
  const float* d0w = (const float*)d_in[12];
  const float* d0b = (const float*)d_in[13];
  const float* d2w = (const float*)d_in[14];
  const float* d2b = (const float*)d_in[15];
  const float* d4w = (const float*)d_in[16];
  const float* d4b = (const float*)d_in[17];
  const float* d6w = (const float*)d_in[18];
  const float* d6b = (const float*)d_in[19];
  const float* d7w = (const float*)d_in[20];
  const float* d7b = (const float*)d_in[21];
  const float* pw  = (const float*)d_in[22];
  const float* pb  = (const float*)d_in[23];

  char* ws = (char*)d_ws;
  const size_t MB = 1024 * 1024;
  // Airtight layout (peak 194 MiB):
  _Float16* Xn16 = (_Float16*)(ws + 0);
  _Float16* Xt16 = (_Float16*)(ws + 16 * MB);
  float* X32f = (float*)(ws + 32 * MB);
  float* f1   = (float*)(ws + 64 * MB);
  float* f2   = (float*)(ws + 96 * MB);
  float* f3   = (float*)(ws + 112 * MB);
  float* p1   = (float*)(ws + 120 * MB);
  float* p2   = (float*)(ws + 128 * MB);
  float* p3   = (float*)(ws + 132 * MB);
  float* f4   = (float*)(ws + 134 * MB);
  float* o0   = (float*)(ws + 138 * MB);
  float* u0   = (float*)(ws + 140 * MB);
  float* o1   = (float*)(ws + 148 * MB);
  float* u1   = (float*)(ws + 32 * MB);
  float* o2   = (float*)(ws + 160 * MB);
  float* u2   = (float*)(ws + 96 * MB);
  float* o3   = (float*)(ws + 160 * MB);
  _Float16* gbufA = (_Float16*)(ws + 32 * MB);
  _Float16* gbufB = (_Float16*)(ws + 80 * MB);
  _Float16* om1  = (_Float16*)(ws + 128 * MB);
  _Float16* om2  = (_Float16*)(ws + 144 * MB);
  _Float16* omT1 = (_Float16*)(ws + 0);
  _Float16* omT2 = (_Float16*)(ws + 160 * MB);
  float* omfin = (float*)(ws + 32 * MB);
  char* wz = ws + 192 * MB;
  float* wmf  = (float*)wz;
  float* wc1f = wmf + 864;
  float* wpkf = wc1f + 864;
  _Float16* wc2p = (_Float16*)(wpkf + 864);
  _Float16* wc3p = wc2p + 19456;
  _Float16* wc4p = wc3p + 77824;
  _Float16* wd2p = wc4p + 311296;
  _Float16* wd4p = wd2p + 155648;
  _Float16* wd6p = wd4p + 77824;
  _Float16* wd7p = wd6p + 19456;

  // Determinism guard: zero all used workspace every call.
  hipMemsetAsync(d_ws, 0, 194 * MB, stream);

  dim3 blk(256);
  // One merged pack launch; 1152 blocks covers the largest pack (c4w: 294912).
  k_packall<<<dim3(1152, 10), blk, 0, stream>>>(mw, c1w, pw, c2w, c3w, c4w,
                                                d2w, d4w, d6w, d7w, wz);

  // Phase A
  k_conv3x3f<3, 32><<<dim3(256, 1, 4), blk, 0, stream>>>(x, wmf, mb, X32f, 3, 256, 256, 32, 32);
  k_xcvt<<<dim3(8, 8, 128), dim3(32, 8), 0, stream>>>(X32f, Xn16, Xt16);
  k_conv3x3f<3, 32><<<dim3(256, 1, 4), blk, 0, stream>>>(rgb, wc1f, c1b, f1, 3, 256, 256, 32, 32);

  // Phase B: encoder
  k_pool<<<dim3(64, 32, 4), blk, 0, stream>>>(f1, p1, 32, 256, 256);
  k_convh<4, 2, 2, 0, 0><<<dim3(128, 1, 4), dim3(256), 0, stream>>>(p1, wc2p, c2b, nullptr, f2, nullptr, 128, 128, 64, 0, 64, 0);
  k_pool<<<dim3(16, 64, 4), blk, 0, stream>>>(f2, p2, 64, 128, 128);
  k_convh<2, 2, 4, 0, 0><<<dim3(64, 2, 4), dim3(128), 0, stream>>>(p2, wc3p, c3b, nullptr, f3, nullptr, 64, 64, 128, 0, 128, 0);
  k_pool<<<dim3(4, 128, 4), blk, 0, stream>>>(f3, p3, 128, 64, 64);
  k_convh<2, 2, 8, 0, 0><<<dim3(16, 4, 4), dim3(128), 0, stream>>>(p3, wc4p, c4b, nullptr, f4, nullptr, 32, 32, 256, 0, 256, 0);
  k_conv1x1<<<dim3(4, 128, 4), blk, 0, stream>>>(f4, d0w, d0b, o0, 256, 128, 32, 32);

  // Phase C: decoder
  k_up2<<<dim3(16, 128, 4), blk, 0, stream>>>(o0, u0, 128, 32, 32);
  k_convh<2, 2, 8, 1, 0><<<dim3(64, 2, 4), dim3(128), 0, stream>>>(u0, wd2p, d2b, f3, o1, nullptr, 64, 64, 128, 0, 128, 0);
  k_up2<<<dim3(64, 128, 4), blk, 0, stream>>>(o1, u1, 128, 64, 64);
  k_convh<4, 2, 8, 1, 0><<<dim3(128, 1, 4), dim3(256), 0, stream>>>(u1, wd4p, d4b, f2, o2, nullptr, 128, 128, 64, 0, 64, 0);
  k_up2<<<dim3(256, 64, 4), blk, 0, stream>>>(o2, u2, 64, 128, 128);
  k_convh<4, 1, 4, 1, 0><<<dim3(512, 1, 4), dim3(256), 0, stream>>>(u2, wd6p, d6b, f1, o3, nullptr, 256, 256, 32, 0, 32, 0);

  // Phase D: vertical guide conv (k=2 -> gbufA, k=3 -> gbufB), pair scan
  k_convh<4, 3, 2, 0, 1><<<dim3(512, 2, 4), dim3(256), 0, stream>>>(o3, wd7p, d7b, nullptr, gbufA, gbufB, 256, 256, 384, 192, 96, 0);
  k_prop_pair<<<dim3(256), dim3(64), 0, stream>>>(Xn16, gbufA, gbufB, om1, om2, 256, 256);

  // Phase E: horizontal guide conv (narrow tile TW=4, 64B transposed stores)
  k_convh<4, 3, 2, 2, 1, 4><<<dim3(512, 2, 4), dim3(256), 0, stream>>>(o3, wd7p, d7b, nullptr, gbufA, gbufB, 256, 256, 384, 0, 96, 0);
  k_prop_pair<<<dim3(256), dim3(64), 0, stream>>>(Xt16, gbufA, gbufB, omT1, omT2, 256, 256);

  // Final: max of 4 buffers -> f32, then conv
  k_max4<<<dim3(8, 8, 128), blk, 0, stream>>>(om1, om2, omT1, omT2, omfin);
  k_conv3x3f<32, 3><<<dim3(256, 1, 4), blk, 0, stream>>>(omfin, wpkf, pb, (float*)d_out, 32, 256, 256, 3, 3);
}

// Round 17
// 843.632 us; speedup vs baseline: 1.0893x; 1.0893x over previous
//
#include <hip/hip_runtime.h>
#include <cstddef>
#include <cstdint>

#define DEVINL __device__ __forceinline__

typedef __attribute__((ext_vector_type(8))) _Float16 half8v;
typedef __attribute__((ext_vector_type(4))) _Float16 half4v;
typedef __attribute__((ext_vector_type(16))) float f32x16;

constexpr int cmax(int a, int b) { return a > b ? a : b; }

// ---------------------------------------------------------------------------
// SPN forward, MI355X gfx950. B=4, H=W=256, NF=32.
// Round 17: channel-interleaved fp16 o3 ([b][y][x][32]) — d6 writes it
// (MODE 3), guide convs read it (IN16=1): 32B-contiguous halo staging.
// ---------------------------------------------------------------------------

// ---------- merged weight pack: blockIdx.y = pack id ----------
__global__ __launch_bounds__(256) void k_packall(
    const float* __restrict__ mw, const float* __restrict__ c1w,
    const float* __restrict__ pw,
    const float* __restrict__ c2w, const float* __restrict__ c3w,
    const float* __restrict__ c4w, const float* __restrict__ d2w,
    const float* __restrict__ d4w, const float* __restrict__ d6w,
    const float* __restrict__ d7w, char* __restrict__ wz)
{
  const int p = blockIdx.y;
  const int e = blockIdx.x * 256 + threadIdx.x;
  if (p < 3) {
    const float* src = (p == 0) ? mw : (p == 1) ? c1w : pw;
    const int ci = (p == 2) ? 32 : 3;
    const int co = (p == 2) ? 3 : 32;
    const int n = co * ci * 9;
    if (e >= n) return;
    float* dst = (float*)wz + (p == 0 ? 0 : (p == 1 ? 864 : 1728));
    int cco = e / (ci * 9);
    int r   = e - cco * ci * 9;
    int cci = r / 9;
    int k   = r - cci * 9;
    dst[(cci * 9 + k) * co + cco] = src[e];
  } else {
    const float* src; int ci, co; size_t off;
    switch (p) {
      case 3:  src = c2w; ci = 32;  co = 64;  off = 0;      break;
      case 4:  src = c3w; ci = 64;  co = 128; off = 19456;  break;
      case 5:  src = c4w; ci = 128; co = 256; off = 97280;  break;
      case 6:  src = d2w; ci = 128; co = 128; off = 408576; break;
      case 7:  src = d4w; ci = 128; co = 64;  off = 564224; break;
      case 8:  src = d6w; ci = 64;  co = 32;  off = 642048; break;
      default: src = d7w; ci = 32;  co = 384; off = 661504; break;
    }
    int chunks = ci >> 4;
    int total = co * chunks * 144;
    if (e >= total) return;
    _Float16* dst = (_Float16*)(wz + 2592 * 4) + off;
    int n  = e / (chunks * 144);
    int r2 = e - n * chunks * 144;
    int cb = r2 / 144;
    int k  = r2 - cb * 144;
    int tap = k >> 4, cci = k & 15;
    float v = src[((size_t)n * ci + cb * 16 + cci) * 9 + tap];
    dst[((size_t)cb * co + n) * 152 + k] = (_Float16)v;
  }
}

// ---------- fp16 MFMA implicit-GEMM conv 3x3 pad 1, stage-once halo ----------
// Tile: MT = NWM*32 pixels = (MT/TW) rows x TW cols.
// MODE 0: f32 out = conv+bias (NCHW).  MODE 1: f32 out = elu(conv+bias)+skip.
// MODE 2 (+GATES): transposed per-plane store.  MODE 3: elu(conv+bias)+skip
// stored channel-INTERLEAVED fp16 [b][y][x][N_BLK] (needs N_BLK==32, GATES=0).
// IN16=1: input is interleaved fp16 [b][y][x][CHUNKS*16].
// GATES=1: blockIdx.y selects direction half: nb = n0 + y*96.
template<int NWM, int NACC, int CHUNKS, int MODE, int GATES, int TW = 16, int IN16 = 0>
__global__ __launch_bounds__(NWM * 64) void k_convh(
    const void* __restrict__ inv, const _Float16* __restrict__ wpk,
    const float* __restrict__ bias, const float* __restrict__ skip,
    void* __restrict__ outv, void* __restrict__ outv2,
    int H, int W, int wCout, int n0, int outC, int oco0)
{
  static_assert(GATES == 0 || NACC == 3, "GATES needs NACC==3");
  static_assert(TW == 16 || MODE == 2, "narrow tile only for MODE 2");
  static_assert(MODE != 3 || NACC == 1, "MODE 3 needs N_BLK==32");
  constexpr int NTHR = NWM * 64;
  constexpr int MT = NWM * 32;
  constexpr int RT = MT / TW;
  constexpr int RHh = RT + 2;
  constexpr int CW = TW + 2;
  constexpr int AENT = RHh * CW;
  constexpr int N_BLK = NACC * 32;
  constexpr int APS = 24;
  constexpr int A_BYTES = AENT * APS * 2;
  constexpr int B_BYTES = N_BLK * 152 * 2;
  constexpr int MPF = MT + 2;
  constexpr int MPH = 132;
  constexpr int EP_BYTES = GATES ? (96 * MPH * 2) : (N_BLK * MPF * 4);
  constexpr int SMEM = cmax(A_BYTES + B_BYTES, EP_BYTES);
  constexpr int ICH = CHUNKS * 16;

  const int tid = threadIdx.x;
  const int wave = tid >> 6, lane = tid & 63;
  const int wm = wave;
  const int tiles_x = W / TW;
  const int tx0 = (blockIdx.x % tiles_x) * TW;
  const int ty0 = (blockIdx.x / tiles_x) * RT;
  const int b = blockIdx.z;
  const int nb = n0 + blockIdx.y * N_BLK;
  const int ocb = oco0 + blockIdx.y * N_BLK;

  __shared__ __align__(16) char smem[SMEM];
  _Float16* Ah = (_Float16*)smem;
  _Float16* Bh = (_Float16*)(smem + A_BYTES);

  f32x16 acc[NACC] = {};

  const size_t ps = (size_t)H * W;
  const float* inbf = (const float*)inv + (size_t)b * (size_t)ICH * ps;
  const _Float16* inbh = (const _Float16*)inv + (size_t)b * ps * ICH;

  for (int cb = 0; cb < CHUNKS; ++cb) {
    __syncthreads();
    // ---- stage A: halo tile, 16 channels ----
    for (int e = tid; e < AENT; e += NTHR) {
      int r = e / CW, c = e - r * CW;
      int gy = ty0 + r - 1, gx = tx0 + c - 1;
      bool ok = (unsigned)gy < (unsigned)H && (unsigned)gx < (unsigned)W;
      half8v v0{}, v1{};
      if (IN16) {
        if (ok) {
          const _Float16* src = inbh + ((size_t)gy * W + gx) * ICH + cb * 16;
          v0 = *(const half8v*)src;
          v1 = *(const half8v*)(src + 8);
        }
      } else {
        const float* src = inbf + (size_t)(cb * 16) * ps + (size_t)gy * W + gx;
#pragma unroll
        for (int j = 0; j < 8; ++j)
          v0[j] = ok ? (_Float16)src[(size_t)j * ps] : (_Float16)0.f;
#pragma unroll
        for (int j = 0; j < 8; ++j)
          v1[j] = ok ? (_Float16)src[(size_t)(j + 8) * ps] : (_Float16)0.f;
      }
      *(half8v*)&Ah[e * APS] = v0;
      *(half8v*)&Ah[e * APS + 8] = v1;
    }
    // ---- stage B (per chunk) ----
    {
      const _Float16* wsrc = wpk + ((size_t)cb * wCout + nb) * 152;
      for (int e = tid; e < N_BLK * 19; e += NTHR)
        *(uint4*)&Bh[e * 8] = *(const uint4*)(wsrc + e * 8);
    }
    __syncthreads();
    // ---- MFMA: 9 shifted tap-reads x NACC ----
    const int am = wm * 32 + (lane & 31);
    const int r0 = am / TW, c0 = am % TW;
    const int kh = lane >> 5;
    const _Float16* Ab = Ah + kh * 8;
    const _Float16* Bb = Bh + kh * 8;
#pragma unroll
    for (int ks = 0; ks < 9; ++ks) {
      const int dy = ks / 3, dx = ks - dy * 3;
      half8v af = *(const half8v*)(Ab + ((r0 + dy) * CW + (c0 + dx)) * APS);
#pragma unroll
      for (int na = 0; na < NACC; ++na) {
        const int bn = na * 32 + (lane & 31);
        half8v bf = *(const half8v*)(Bb + bn * 152 + ks * 16);
        acc[na] = __builtin_amdgcn_mfma_f32_32x32x16_f16(af, bf, acc[na], 0, 0, 0);
      }
    }
  }

  __syncthreads();

  if (GATES) {
    _Float16* EPH = (_Float16*)smem;
    const int c = lane & 31;
    const float bv0 = bias[nb + c];
    const float bv1 = bias[nb + 32 + c];
    const float bv2 = bias[nb + 64 + c];
#pragma unroll
    for (int i = 0; i < 16; ++i) {
      int m = wm * 32 + (i & 3) + 8 * (i >> 2) + 4 * (lane >> 5);
      float g1 = acc[0][i] + bv0;
      float g2 = acc[GATES ? 1 : 0][i] + bv1;
      float g3 = acc[GATES ? 2 : 0][i] + bv2;
      float s = fabsf(g1) + fabsf(g2) + fabsf(g3);
      if (s >= 1.f) { float r = 1.f / s; g1 *= r; g2 *= r; g3 *= r; }
      EPH[(size_t)(0 * 32 + c) * MPH + m] = (_Float16)g1;
      EPH[(size_t)(1 * 32 + c) * MPH + m] = (_Float16)g2;
      EPH[(size_t)(2 * 32 + c) * MPH + m] = (_Float16)g3;
    }
    __syncthreads();
    _Float16* outh = (_Float16*)(blockIdx.y ? outv2 : outv);
    if (MODE == 2) {
      const int TOT = 96 * TW;
      for (int r = tid; r < TOT; r += NTHR) {
        int gc = r / TW, x = r % TW;
        const _Float16* ep = EPH + (size_t)gc * MPH + x;
        _Float16 v[RT];
#pragma unroll
        for (int y = 0; y < RT; ++y) v[y] = ep[y * TW];
        size_t base = ((size_t)(b * 96 + gc) * W + tx0 + x) * (size_t)H + ty0;
#pragma unroll
        for (int j = 0; j < RT / 8; ++j)
          *(uint4*)(outh + base + j * 8) = *(const uint4*)(v + j * 8);
      }
    } else {
      const int TOT = 96 * RT;
      for (int r = tid; r < TOT; r += NTHR) {
        int gc = r / RT, y = r - gc * RT;
        const uint2* ep = (const uint2*)(EPH + (size_t)gc * MPH + y * TW);
        uint2 v0 = ep[0], v1 = ep[1], v2 = ep[2], v3 = ep[3];
        size_t base = ((size_t)(b * 96 + gc) * H + ty0 + y) * (size_t)W + tx0;
        *(uint2*)(outh + base + 0)  = v0;
        *(uint2*)(outh + base + 4)  = v1;
        *(uint2*)(outh + base + 8)  = v2;
        *(uint2*)(outh + base + 12) = v3;
      }
    }
  } else {
    float* EP = (float*)smem;
    float bv[NACC];
#pragma unroll
    for (int na = 0; na < NACC; ++na) bv[na] = bias[nb + na * 32 + (lane & 31)];
#pragma unroll
    for (int na = 0; na < NACC; ++na) {
      const int c = na * 32 + (lane & 31);
#pragma unroll
      for (int i = 0; i < 16; ++i) {
        int m = wm * 32 + (i & 3) + 8 * (i >> 2) + 4 * (lane >> 5);
        EP[(size_t)c * MPF + m] = acc[na][i] + bv[na];
      }
    }
    __syncthreads();
    if (MODE == 3) {
      // pass 1: elu + skip in place (rows coalesced)
      const int TOT = N_BLK * RT;
      for (int r = tid; r < TOT; r += NTHR) {
        int c = r / RT, y = r - c * RT;
        float* ep = EP + (size_t)c * MPF + y * 16;
        size_t base = (((size_t)b * outC + ocb + c) * H + ty0 + y) * (size_t)W + tx0;
#pragma unroll
        for (int j = 0; j < 4; ++j) {
          float4 sk = *(const float4*)(skip + base + 4 * j);
          float2 a = *(const float2*)(ep + 4 * j);
          float2 bb = *(const float2*)(ep + 4 * j + 2);
          float e0 = a.x > 0.f ? a.x : expm1f(a.x);
          float e1 = a.y > 0.f ? a.y : expm1f(a.y);
          float e2 = bb.x > 0.f ? bb.x : expm1f(bb.x);
          float e3 = bb.y > 0.f ? bb.y : expm1f(bb.y);
          float2 o0 = {e0 + sk.x, e1 + sk.y};
          float2 o1 = {e2 + sk.z, e3 + sk.w};
          *(float2*)(ep + 4 * j) = o0;
          *(float2*)(ep + 4 * j + 2) = o1;
        }
      }
      __syncthreads();
      // pass 2: per-pixel interleaved fp16 store (64B contiguous)
      _Float16* outh = (_Float16*)outv;
      for (int px = tid; px < MT; px += NTHR) {
        int y = px / TW, xx = px % TW;
        _Float16 v[32];
#pragma unroll
        for (int c = 0; c < 32; ++c) v[c] = (_Float16)EP[(size_t)c * MPF + px];
        size_t base = (((size_t)b * H + ty0 + y) * W + tx0 + xx) * 32;
#pragma unroll
        for (int j = 0; j < 4; ++j)
          *(uint4*)(outh + base + j * 8) = *(const uint4*)(v + j * 8);
      }
    } else {
      float* out = (float*)outv;
      const int TOT = N_BLK * RT;
      for (int r = tid; r < TOT; r += NTHR) {
        int c = r / RT, y = r - c * RT;
        const float2* ep = (const float2*)(EP + (size_t)c * MPF + y * 16);
        float v[16];
#pragma unroll
        for (int j = 0; j < 8; ++j) {
          float2 t = ep[j];
          v[2 * j] = t.x; v[2 * j + 1] = t.y;
        }
        size_t base = (((size_t)b * outC + ocb + c) * H + ty0 + y) * (size_t)W + tx0;
        if (MODE == 1) {
#pragma unroll
          for (int j = 0; j < 4; ++j) {
            float4 sk = *(const float4*)(skip + base + 4 * j);
            float e0 = v[4*j+0] > 0.f ? v[4*j+0] : expm1f(v[4*j+0]);
            float e1 = v[4*j+1] > 0.f ? v[4*j+1] : expm1f(v[4*j+1]);
            float e2 = v[4*j+2] > 0.f ? v[4*j+2] : expm1f(v[4*j+2]);
            float e3 = v[4*j+3] > 0.f ? v[4*j+3] : expm1f(v[4*j+3]);
            v[4*j+0] = e0 + sk.x; v[4*j+1] = e1 + sk.y;
            v[4*j+2] = e2 + sk.z; v[4*j+3] = e3 + sk.w;
          }
        }
#pragma unroll
        for (int j = 0; j < 4; ++j)
          *(float4*)(out + base + 4 * j) = *(const float4*)(v + 4 * j);
      }
    }
  }
}

// ---------- f32 tiled conv 3x3 (small convs + final) ----------
template<int CI, int CO>
__global__ __launch_bounds__(256) void k_conv3x3f(
    const float* __restrict__ in, const float* __restrict__ wr,
    const float* __restrict__ bias, float* __restrict__ out,
    int Cin, int H, int W, int wstride, int outC)
{
  const int ntx = W >> 4;
  const int tid = threadIdx.x;
  const int tx = tid & 15, ty = tid >> 4;
  const int tx0 = (blockIdx.x % ntx) << 4, ty0 = (blockIdx.x / ntx) << 4;
  const int b = blockIdx.z;

  __shared__ float sh[CI * 324];

  float acc[CO];
#pragma unroll
  for (int co = 0; co < CO; ++co) acc[co] = bias[co];

  const float* inb = in + (size_t)b * Cin * H * W;

  for (int cb = 0; cb < Cin; cb += CI) {
    __syncthreads();
    for (int e = tid; e < CI * 324; e += 256) {
      int ci = e / 324;
      int rr = e - ci * 324;
      int r = rr / 18, c = rr - r * 18;
      int gh = ty0 + r - 1, gw = tx0 + c - 1;
      float v = 0.f;
      if ((unsigned)gh < (unsigned)H && (unsigned)gw < (unsigned)W)
        v = inb[(size_t)(cb + ci) * H * W + (size_t)gh * W + gw];
      sh[e] = v;
    }
    __syncthreads();
#pragma unroll 1
    for (int ci = 0; ci < CI; ++ci) {
      float v[9];
      const float* sp = sh + ci * 324 + ty * 18 + tx;
#pragma unroll
      for (int kh = 0; kh < 3; ++kh)
#pragma unroll
        for (int kw = 0; kw < 3; ++kw)
          v[kh * 3 + kw] = sp[kh * 18 + kw];
      const float* wp = wr + (size_t)((cb + ci) * 9) * wstride;
#pragma unroll
      for (int k = 0; k < 9; ++k)
#pragma unroll
        for (int co = 0; co < CO; ++co)
          acc[co] = fmaf(wp[(size_t)k * wstride + co], v[k], acc[co]);
    }
  }
#pragma unroll
  for (int co = 0; co < CO; ++co)
    out[(((size_t)b * outC + co) * H + ty0 + ty) * W + tx0 + tx] = acc[co];
}

// ---------- max of 4 scan outputs -> f32 natural buffer ----------
__global__ __launch_bounds__(256) void k_max4(
    const _Float16* __restrict__ om1, const _Float16* __restrict__ om2,
    const _Float16* __restrict__ omT1, const _Float16* __restrict__ omT2,
    float* __restrict__ out)
{
  __shared__ float t[32][33];
  const int z = blockIdx.z;
  const int x0 = blockIdx.x * 32, y0 = blockIdx.y * 32;
  const int tx = threadIdx.x & 31, ty = threadIdx.x >> 5;
  const size_t ps = 65536;
  const size_t zb = (size_t)z * ps;
#pragma unroll
  for (int j = 0; j < 32; j += 8) {
    size_t p = zb + (size_t)(x0 + ty + j) * 256 + (y0 + tx);
    t[ty + j][tx] = fmaxf((float)omT1[p], (float)omT2[p]);
  }
  __syncthreads();
#pragma unroll
  for (int j = 0; j < 32; j += 8) {
    size_t p = zb + (size_t)(y0 + ty + j) * 256 + (x0 + tx);
    float v = fmaxf((float)om1[p], (float)om2[p]);
    out[p] = fmaxf(v, t[tx][ty + j]);
  }
}

// ---------- conv 1x1 (f32) ----------
__global__ __launch_bounds__(256) void k_conv1x1(
    const float* __restrict__ in, const float* __restrict__ wgt,
    const float* __restrict__ bias, float* __restrict__ out,
    int Cin, int Cout, int H, int W)
{
  int hw = blockIdx.x * 256 + threadIdx.x;
  if (hw >= H * W) return;
  int co = blockIdx.y, b = blockIdx.z;
  const float* ip = in + (size_t)b * Cin * H * W + hw;
  const float* wp = wgt + (size_t)co * Cin;
  float acc = bias[co];
  for (int ci = 0; ci < Cin; ++ci) acc += wp[ci] * ip[(size_t)ci * H * W];
  out[((size_t)b * Cout + co) * H * W + hw] = acc;
}

// ---------- relu + maxpool 3x3 stride 2 pad 1 ----------
__global__ __launch_bounds__(256) void k_pool(
    const float* __restrict__ in, float* __restrict__ out, int C, int H, int W)
{
  int Ho = H >> 1, Wo = W >> 1;
  int hw = blockIdx.x * 256 + threadIdx.x;
  if (hw >= Ho * Wo) return;
  int ow = hw % Wo, oh = hw / Wo;
  int c = blockIdx.y, b = blockIdx.z;
  const float* p = in + ((size_t)(b * C + c) * H) * W;
  float m = 0.f;
#pragma unroll
  for (int dh = -1; dh <= 1; ++dh) {
    int ih = 2 * oh + dh;
    if ((unsigned)ih >= (unsigned)H) continue;
    const float* r = p + (size_t)ih * W;
#pragma unroll
    for (int dw = -1; dw <= 1; ++dw) {
      int iw = 2 * ow + dw;
      if ((unsigned)iw >= (unsigned)W) continue;
      m = fmaxf(m, r[iw]);
    }
  }
  out[((size_t)(b * C + c) * Ho + oh) * Wo + ow] = m;
}

// ---------- bilinear 2x upsample ----------
__global__ __launch_bounds__(256) void k_up2(
    const float* __restrict__ in, float* __restrict__ out, int C, int H, int W)
{
  int Ho = H * 2, Wo = W * 2;
  int hw = blockIdx.x * 256 + threadIdx.x;
  if (hw >= Ho * Wo) return;
  int ow = hw % Wo, oh = hw / Wo;
  int c = blockIdx.y, b = blockIdx.z;
  int ih = oh >> 1, iw = ow >> 1;
  int ih0, ih1, iw0, iw1; float fh0, fw0;
  if (oh & 1) { ih0 = ih; ih1 = min(ih + 1, H - 1); fh0 = 0.75f; }
  else        { ih0 = max(ih - 1, 0); ih1 = ih;     fh0 = 0.25f; }
  if (ow & 1) { iw0 = iw; iw1 = min(iw + 1, W - 1); fw0 = 0.75f; }
  else        { iw0 = max(iw - 1, 0); iw1 = iw;     fw0 = 0.25f; }
  const float* p = in + ((size_t)(b * C + c) * H) * W;
  float v = fh0 * (fw0 * p[(size_t)ih0 * W + iw0] + (1.f - fw0) * p[(size_t)ih0 * W + iw1])
          + (1.f - fh0) * (fw0 * p[(size_t)ih1 * W + iw0] + (1.f - fw0) * p[(size_t)ih1 * W + iw1]);
  out[((size_t)(b * C + c) * Ho + oh) * Wo + ow] = v;
}

// ---------- X f32 -> fp16 natural + fp16 transposed ----------
__global__ void k_xcvt(const float* __restrict__ in, _Float16* __restrict__ xn,
                       _Float16* __restrict__ xt)
{
  __shared__ _Float16 t[32][33];
  int z = blockIdx.z;
  int x0 = blockIdx.x * 32, y0 = blockIdx.y * 32;
  int tx = threadIdx.x, ty = threadIdx.y;
  const float* ip = in + (size_t)z * 65536;
#pragma unroll
  for (int j = 0; j < 32; j += 8) {
    float v = ip[(size_t)(y0 + ty + j) * 256 + x0 + tx];
    xn[(size_t)z * 65536 + (size_t)(y0 + ty + j) * 256 + x0 + tx] = (_Float16)v;
    t[ty + j][tx] = (_Float16)v;
  }
  __syncthreads();
#pragma unroll
  for (int j = 0; j < 32; j += 8)
    xt[(size_t)z * 65536 + (size_t)(x0 + ty + j) * 256 + y0 + tx] = t[tx][ty + j];
}

// ---------- gated scan core: chunk-contiguous lanes, 2 shuffles/step ----------
DEVINL void gl_lds16p(const void* g, void* lds) {
  __builtin_amdgcn_global_load_lds(
      (const __attribute__((address_space(1))) unsigned int*)g,
      (__attribute__((address_space(3))) unsigned int*)lds, 16, 0, 0);
}

template<int REV>
DEVINL void prop_core(const _Float16* xp, const _Float16* g1,
                      const _Float16* g2, const _Float16* g3,
                      _Float16* op, int S, int P, int lane,
                      _Float16* bx, _Float16* h1, _Float16* h2, _Float16* h3)
{
  float r0 = 0.f, r1 = 0.f, r2 = 0.f, r3 = 0.f;
  int cur = 0;

  auto stage = [&](int buf, int s0) {
#pragma unroll
    for (int v = 0; v < 8; ++v) {
      size_t ro = (size_t)(s0 + 2 * v) * P + lane * 8;
      gl_lds16p(xp + ro, bx + buf * 4096 + v * 512);
      gl_lds16p(g1 + ro, h1 + buf * 4096 + v * 512);
      gl_lds16p(g2 + ro, h2 + buf * 4096 + v * 512);
      gl_lds16p(g3 + ro, h3 + buf * 4096 + v * 512);
    }
  };

  stage(0, REV ? (S - 16) : 0);
  const int NT = S / 16;
  for (int t = 0; t < NT; ++t) {
    const int s0 = REV ? (S - 16 - t * 16) : (t * 16);
    asm volatile("s_waitcnt vmcnt(0)" ::: "memory");
    if (t + 1 < NT) stage(cur ^ 1, REV ? (s0 - 16) : (s0 + 16));

#pragma unroll
    for (int u = 0; u < 16; ++u) {
      const int e = REV ? (15 - u) : u;
      half4v xv = *(const half4v*)(bx + cur * 4096 + e * 256 + 4 * lane);
      half4v a1 = *(const half4v*)(h1 + cur * 4096 + e * 256 + 4 * lane);
      half4v a2 = *(const half4v*)(h2 + cur * 4096 + e * 256 + 4 * lane);
      half4v a3 = *(const half4v*)(h3 + cur * 4096 + e * 256 + 4 * lane);

      float hu0 = __shfl_up(r3, 1);
      float hd3 = __shfl_down(r0, 1);
      if (lane == 0)  hu0 = 0.f;
      if (lane == 63) hd3 = 0.f;

      float o0 = r0, o1 = r1, o2 = r2, o3v = r3;
      float x0 = xv[0], x1 = xv[1], x2 = xv[2], x3 = xv[3];
      float a10 = a1[0], a11 = a1[1], a12 = a1[2], a13 = a1[3];
      float a20 = a2[0], a21 = a2[1], a22 = a2[2], a23 = a2[3];
      float a30 = a3[0], a31 = a3[1], a32 = a3[2], a33 = a3[3];

      r0 = (1.f - a10 - a20 - a30) * x0 + a10 * hu0 + a20 * o0 + a30 * o1;
      r1 = (1.f - a11 - a21 - a31) * x1 + a11 * o0  + a21 * o1 + a31 * o2;
      r2 = (1.f - a12 - a22 - a32) * x2 + a12 * o1  + a22 * o2 + a32 * o3v;
      r3 = (1.f - a13 - a23 - a33) * x3 + a13 * o2  + a23 * o3v + a33 * hd3;

      half4v hv; hv[0] = (_Float16)r0; hv[1] = (_Float16)r1;
      hv[2] = (_Float16)r2; hv[3] = (_Float16)r3;
      *(half4v*)(op + (size_t)(s0 + e) * P + 4 * lane) = hv;
    }
    cur ^= 1;
  }
}

// dir = blockIdx.x>>7: 0 -> fwd (GA -> omA), 1 -> rev (GB -> omB).
__global__ __launch_bounds__(64) void k_prop_pair(
    const _Float16* __restrict__ Xh,
    const _Float16* __restrict__ GA, const _Float16* __restrict__ GB,
    _Float16* __restrict__ omA, _Float16* __restrict__ omB, int S, int P)
{
  const int dir = blockIdx.x >> 7;
  const int plane = blockIdx.x & 127;
  const int b = plane >> 5, c = plane & 31;
  const int lane = threadIdx.x;
  const size_t ps = (size_t)S * P;

  __shared__ __align__(16) _Float16 bx[2 * 4096];
  __shared__ __align__(16) _Float16 h1[2 * 4096];
  __shared__ __align__(16) _Float16 h2[2 * 4096];
  __shared__ __align__(16) _Float16 h3[2 * 4096];

  const _Float16* xp = Xh + (size_t)plane * ps;
  const _Float16* G = dir ? GB : GA;
  const _Float16* g1 = G + ((size_t)b * 96 + c) * ps;
  const _Float16* g2 = g1 + (size_t)32 * ps;
  const _Float16* g3 = g1 + (size_t)64 * ps;
  _Float16* op = (dir ? omB : omA) + (size_t)plane * ps;

  if (dir == 0) prop_core<0>(xp, g1, g2, g3, op, S, P, lane, bx, h1, h2, h3);
  else          prop_core<1>(xp, g1, g2, g3, op, S, P, lane, bx, h1, h2, h3);
}

// ---------------------------------------------------------------------------
extern "C" void kernel_launch(void* const* d_in, const int* in_sizes, int n_in,
                              void* d_out, int out_size, void* d_ws, size_t ws_size,
                              hipStream_t stream)
{
  const float* x   = (const float*)d_in[0];
  const float* rgb = (const float*)d_in[1];
  const float* mw  = (const float*)d_in[2];
  const float* mb  = (const float*)d_in[3];
  const float* c1w = (const float*)d_in[4];
  const float* c1b = (const float*)d_in[5];
  const float* c2w = (const float*)d_in[6];
  const float* c2b = (const float*)d_in[7];
  const float* c3w = (const float*)d_in[8];
  const float* c3b = (const float*)d_in[9];
  const float* c4w = (const float*)d_in[10];
  const float* c4b = (const float*)d_in[11];
  const float* d0w = (const float*)d_in[12];
  const float* d0b = (const float*)d_in[13];
  const float* d2w = (const float*)d_in[14];
  const float* d2b = (const float*)d_in[15];
  const float* d4w = (const float*)d_in[16];
  const float* d4b = (const float*)d_in[17];
  const float* d6w = (const float*)d_in[18];
  const float* d6b = (const float*)d_in[19];
  const float* d7w = (const float*)d_in[20];
  const float* d7b = (const float*)d_in[21];
  const float* pw  = (const float*)d_in[22];
  const float* pb  = (const float*)d_in[23];

  char* ws = (char*)d_ws;
  const size_t MB = 1024 * 1024;
  // Airtight layout (peak 194 MiB):
  _Float16* Xn16 = (_Float16*)(ws + 0);
  _Float16* Xt16 = (_Float16*)(ws + 16 * MB);
  float* X32f = (float*)(ws + 32 * MB);
  float* f1   = (float*)(ws + 64 * MB);
  float* f2   = (float*)(ws + 96 * MB);
  float* f3   = (float*)(ws + 112 * MB);
  float* p1   = (float*)(ws + 120 * MB);
  float* p2   = (float*)(ws + 128 * MB);
  float* p3   = (float*)(ws + 132 * MB);
  float* f4   = (float*)(ws + 134 * MB);
  float* o0   = (float*)(ws + 138 * MB);
  float* u0   = (float*)(ws + 140 * MB);
  float* o1   = (float*)(ws + 148 * MB);
  float* u1   = (float*)(ws + 32 * MB);
  float* o2   = (float*)(ws + 160 * MB);
  float* u2   = (float*)(ws + 96 * MB);
  _Float16* o3h = (_Float16*)(ws + 160 * MB);   // (4,256,256,32) fp16, 16 MB
  _Float16* gbufA = (_Float16*)(ws + 32 * MB);
  _Float16* gbufB = (_Float16*)(ws + 80 * MB);
  _Float16* om1  = (_Float16*)(ws + 128 * MB);
  _Float16* om2  = (_Float16*)(ws + 144 * MB);
  _Float16* omT1 = (_Float16*)(ws + 0);
  _Float16* omT2 = (_Float16*)(ws + 176 * MB);  // after o3h (dead post-guide)
  float* omfin = (float*)(ws + 32 * MB);
  char* wz = ws + 192 * MB;
  float* wmf  = (float*)wz;
  float* wc1f = wmf + 864;
  float* wpkf = wc1f + 864;
  _Float16* wc2p = (_Float16*)(wpkf + 864);
  _Float16* wc3p = wc2p + 19456;
  _Float16* wc4p = wc3p + 77824;
  _Float16* wd2p = wc4p + 311296;
  _Float16* wd4p = wd2p + 155648;
  _Float16* wd6p = wd4p + 77824;
  _Float16* wd7p = wd6p + 19456;

  // Determinism guard: zero all used workspace every call.
  hipMemsetAsync(d_ws, 0, 194 * MB, stream);

  dim3 blk(256);
  // One merged pack launch; 1152 blocks covers the largest pack (c4w: 294912).
  k_packall<<<dim3(1152, 10), blk, 0, stream>>>(mw, c1w, pw, c2w, c3w, c4w,
                                                d2w, d4w, d6w, d7w, wz);

  // Phase A
  k_conv3x3f<3, 32><<<dim3(256, 1, 4), blk, 0, stream>>>(x, wmf, mb, X32f, 3, 256, 256, 32, 32);
  k_xcvt<<<dim3(8, 8, 128), dim3(32, 8), 0, stream>>>(X32f, Xn16, Xt16);
  k_conv3x3f<3, 32><<<dim3(256, 1, 4), blk, 0, stream>>>(rgb, wc1f, c1b, f1, 3, 256, 256, 32, 32);

  // Phase B: encoder
  k_pool<<<dim3(64, 32, 4), blk, 0, stream>>>(f1, p1, 32, 256, 256);
  k_convh<4, 2, 2, 0, 0><<<dim3(128, 1, 4), dim3(256), 0, stream>>>(p1, wc2p, c2b, nullptr, f2, nullptr, 128, 128, 64, 0, 64, 0);
  k_pool<<<dim3(16, 64, 4), blk, 0, stream>>>(f2, p2, 64, 128, 128);
  k_convh<2, 2, 4, 0, 0><<<dim3(64, 2, 4), dim3(128), 0, stream>>>(p2, wc3p, c3b, nullptr, f3, nullptr, 64, 64, 128, 0, 128, 0);
  k_pool<<<dim3(4, 128, 4), blk, 0, stream>>>(f3, p3, 128, 64, 64);
  k_convh<2, 2, 8, 0, 0><<<dim3(16, 4, 4), dim3(128), 0, stream>>>(p3, wc4p, c4b, nullptr, f4, nullptr, 32, 32, 256, 0, 256, 0);
  k_conv1x1<<<dim3(4, 128, 4), blk, 0, stream>>>(f4, d0w, d0b, o0, 256, 128, 32, 32);

  // Phase C: decoder
  k_up2<<<dim3(16, 128, 4), blk, 0, stream>>>(o0, u0, 128, 32, 32);
  k_convh<2, 2, 8, 1, 0><<<dim3(64, 2, 4), dim3(128), 0, stream>>>(u0, wd2p, d2b, f3, o1, nullptr, 64, 64, 128, 0, 128, 0);
  k_up2<<<dim3(64, 128, 4), blk, 0, stream>>>(o1, u1, 128, 64, 64);
  k_convh<4, 2, 8, 1, 0><<<dim3(128, 1, 4), dim3(256), 0, stream>>>(u1, wd4p, d4b, f2, o2, nullptr, 128, 128, 64, 0, 64, 0);
  k_up2<<<dim3(256, 64, 4), blk, 0, stream>>>(o2, u2, 64, 128, 128);
  // d6: MODE 3 -> channel-interleaved fp16 o3h
  k_convh<4, 1, 4, 3, 0><<<dim3(512, 1, 4), dim3(256), 0, stream>>>(u2, wd6p, d6b, f1, o3h, nullptr, 256, 256, 32, 0, 32, 0);

  // Phase D: vertical guide conv (IN16, k=2 -> gbufA, k=3 -> gbufB), pair scan
  k_convh<4, 3, 2, 0, 1, 16, 1><<<dim3(512, 2, 4), dim3(256), 0, stream>>>(o3h, wd7p, d7b, nullptr, gbufA, gbufB, 256, 256, 384, 192, 96, 0);
  k_prop_pair<<<dim3(256), dim3(64), 0, stream>>>(Xn16, gbufA, gbufB, om1, om2, 256, 256);

  // Phase E: horizontal guide conv (IN16, narrow tile TW=4), pair scan
  k_convh<4, 3, 2, 2, 1, 4, 1><<<dim3(512, 2, 4), dim3(256), 0, stream>>>(o3h, wd7p, d7b, nullptr, gbufA, gbufB, 256, 256, 384, 0, 96, 0);
  k_prop_pair<<<dim3(256), dim3(64), 0, stream>>>(Xt16, gbufA, gbufB, omT1, omT2, 256, 256);

  // Final: max of 4 buffers -> f32, then conv
  k_max4<<<dim3(8, 8, 128), blk, 0, stream>>>(om1, om2, omT1, omT2, omfin);
  k_conv3x3f<32, 3><<<dim3(256, 1, 4), blk, 0, stream>>>(omfin, wpkf, pb, (float*)d_out, 32, 256, 256, 3, 3);
}